// Round 9
// baseline (375.907 us; speedup 1.0000x reference)
//
#include <hip/hip_runtime.h>
#include <math.h>

// WaveRNN: B=4096, T=2048, H=5 tanh RNN + fc1(5x5)+relu + fc2(1x5).
// Round 7: fused DPP version, 275us steady (322 cyc/step), VALUBusy 28%,
// absmax 0.02929688. Latency-bound; in-order issue puts fc1/fc2/store ON the
// wall-clock path even though they're off the dataflow path.
// Round 8: two-phase split. Phase 1 = recurrence only (bit-identical h:
// same fma order, same tanh), buffers 4 steps/lane and streams h to d_ws
// (128B/group coalesced, fire-and-forget). Phase 2 = embarrassingly parallel
// fc1+relu+fc2 over [B][T/4][8][4] h-buffer, memory-bound.
// Fallback: if ws_size < 268MB, launch the round-7 fused kernel (verified).

#define B_ 4096
#define T_ 2048

#define DPPF(v, ctrl) __int_as_float(__builtin_amdgcn_update_dpp(0, __float_as_int(v), (ctrl), 0xF, 0xF, true))
#define QP_X1 0xB1   // lane l <- l^1
#define QP_X2 0x4E   // lane l <- l^2
#define QP_X3 0x1B   // lane l <- l^3
#define RHM   0x141  // lane l <- l^7 (within 8)

__device__ __forceinline__ float precise_tanh(float x) {
    const float L_hi = 1.44269504f;
    const float L_lo = 1.9259630e-8f;
    const float LN2  = 0.69314718f;
    float xc = fminf(fmaxf(x, -15.0f), 15.0f);
    float y2 = xc + xc;
    float a  = y2 * L_hi;
    float dl = fmaf(y2, L_hi, -a);
    dl = fmaf(y2, L_lo, dl);
    float e0 = __builtin_amdgcn_exp2f(a);
    float e  = fmaf(e0, dl * LN2, e0);
    float d  = e + 1.0f;
    float r0 = __builtin_amdgcn_rcpf(d);
    float r  = fmaf(fmaf(-d, r0, 1.0f), r0, r0);
    return fmaf(-2.0f, r, 1.0f);
}

#define EXCHANGE(rr, hh)                                   \
    do {                                                   \
        rr[0] = (hh);                                      \
        rr[1] = DPPF((hh), QP_X1);                         \
        rr[2] = DPPF((hh), QP_X2);                         \
        rr[3] = DPPF((hh), QP_X3);                         \
        rr[7] = DPPF((hh), RHM);                           \
        rr[6] = DPPF(rr[7], QP_X1);                        \
        rr[5] = DPPF(rr[7], QP_X2);                        \
        rr[4] = DPPF(rr[7], QP_X3);                        \
    } while (0)

// ---------------- Phase 1: recurrence only, h -> d_ws ----------------
__global__ __launch_bounds__(64, 1) void rnn_phase1(
    const float* __restrict__ hidden, const float* __restrict__ X,
    const float* __restrict__ W_ih, const float* __restrict__ W_hh,
    const float* __restrict__ b_ih, const float* __restrict__ b_hh,
    float4* __restrict__ hbuf)   // layout [B][T/4][8 lanes] of float4 (u=0..3)
{
    const int lane = threadIdx.x;
    const int j = lane & 7;
    const int grp = (blockIdx.x * 64 + lane) >> 3;

    float w[8];
#pragma unroll
    for (int k = 0; k < 8; ++k) {
        const int c = j ^ k;
        const bool live = (j < 5) && (c < 5);
        w[k] = live ? W_hh[j * 5 + c] : 0.0f;
    }
    const float wih  = (j < 5) ? W_ih[j] : 0.0f;
    const float bias = (j < 5) ? (b_ih[j] + b_hh[j]) : 0.0f;

    float h = (j < 5) ? hidden[grp * 5 + j] : 0.0f;
    float r[8];
    EXCHANGE(r, h);

    const float* __restrict__ xrow = X + (size_t)grp * T_;
    float4*      __restrict__ hout = hbuf + ((size_t)grp * (T_ / 4)) * 8 + j;

    for (int t = 0; t < T_; t += 4) {
        const float4 x4 = *reinterpret_cast<const float4*>(xrow + t);
        float4 hs;
#pragma unroll
        for (int u = 0; u < 4; ++u) {
            const float x = (u == 0) ? x4.x : (u == 1) ? x4.y : (u == 2) ? x4.z : x4.w;
            // bit-identical to round-7: same fma order, same tanh
            float acc = fmaf(x, wih, bias);
            acc = fmaf(w[0], r[0], acc); acc = fmaf(w[1], r[1], acc);
            acc = fmaf(w[2], r[2], acc); acc = fmaf(w[3], r[3], acc);
            acc = fmaf(w[4], r[4], acc); acc = fmaf(w[5], r[5], acc);
            acc = fmaf(w[6], r[6], acc); acc = fmaf(w[7], r[7], acc);
            h = precise_tanh(acc);
            EXCHANGE(r, h);
            if (u == 0) hs.x = h; else if (u == 1) hs.y = h;
            else if (u == 2) hs.z = h; else hs.w = h;
        }
        hout[(t >> 2) * 8] = hs;   // 128B contiguous per group, fire-and-forget
    }
}

// ---------------- Phase 2: fc1 + relu + fc2, massively parallel ----------------
__global__ __launch_bounds__(256) void fc_phase2(
    const float4* __restrict__ hbuf,
    const float* __restrict__ fc1_w, const float* __restrict__ fc1_b,
    const float* __restrict__ fc2_w, const float* __restrict__ fc2_b,
    float* __restrict__ out)
{
    const int g = blockIdx.x * 256 + threadIdx.x;   // 0 .. B*T/4-1, == b*(T/4)+tq
    const int b  = g >> 9;                          // T/4 = 512
    const int tq = g & 511;

    // uniform weights -> scalar loads
    float f1[5][5], fb[5], w2[5];
#pragma unroll
    for (int i = 0; i < 5; ++i) {
#pragma unroll
        for (int c = 0; c < 5; ++c) f1[i][c] = fc1_w[i * 5 + c];
        fb[i] = fc1_b[i];
        w2[i] = fc2_w[i];
    }
    const float b2 = fc2_b[0];

    // h for 4 timesteps: v[c] = (h_c[u0..u3]); only c<5 used
    const float4* src = hbuf + (size_t)g * 8;
    float4 v[5];
#pragma unroll
    for (int c = 0; c < 5; ++c) v[c] = src[c];

    float4 y4;
#pragma unroll
    for (int u = 0; u < 4; ++u) {
        const float h0 = (u==0)?v[0].x:(u==1)?v[0].y:(u==2)?v[0].z:v[0].w;
        const float h1 = (u==0)?v[1].x:(u==1)?v[1].y:(u==2)?v[1].z:v[1].w;
        const float h2 = (u==0)?v[2].x:(u==1)?v[2].y:(u==2)?v[2].z:v[2].w;
        const float h3 = (u==0)?v[3].x:(u==1)?v[3].y:(u==2)?v[3].z:v[3].w;
        const float h4 = (u==0)?v[4].x:(u==1)?v[4].y:(u==2)?v[4].z:v[4].w;
        float y = b2;
#pragma unroll
        for (int i = 0; i < 5; ++i) {
            float gacc = fb[i];
            gacc = fmaf(f1[i][0], h0, gacc);
            gacc = fmaf(f1[i][1], h1, gacc);
            gacc = fmaf(f1[i][2], h2, gacc);
            gacc = fmaf(f1[i][3], h3, gacc);
            gacc = fmaf(f1[i][4], h4, gacc);
            y = fmaf(w2[i], fmaxf(gacc, 0.0f), y);
        }
        if (u == 0) y4.x = y; else if (u == 1) y4.y = y;
        else if (u == 2) y4.z = y; else y4.w = y;
    }
    *reinterpret_cast<float4*>(out + (size_t)b * T_ + 4 * tq) = y4;
}

// ---------------- Fallback: round-7 fused kernel (verified PASS) ----------------
__global__ __launch_bounds__(64, 1) void wavernn_fused(
    const float* __restrict__ hidden, const float* __restrict__ X,
    const float* __restrict__ W_ih, const float* __restrict__ W_hh,
    const float* __restrict__ b_ih, const float* __restrict__ b_hh,
    const float* __restrict__ fc1_w, const float* __restrict__ fc1_b,
    const float* __restrict__ fc2_w, const float* __restrict__ fc2_b,
    float* __restrict__ out)
{
    const int lane = threadIdx.x;
    const int j = lane & 7;
    const int grp = (blockIdx.x * 64 + lane) >> 3;

    float w[8], f[8];
#pragma unroll
    for (int k = 0; k < 8; ++k) {
        const int c = j ^ k;
        const bool live = (j < 5) && (c < 5);
        w[k] = live ? W_hh[j * 5 + c] : 0.0f;
        f[k] = live ? fc1_w[j * 5 + c] : 0.0f;
    }
    const float wih  = (j < 5) ? W_ih[j] : 0.0f;
    const float bias = (j < 5) ? (b_ih[j] + b_hh[j]) : 0.0f;
    const float fb   = (j < 5) ? fc1_b[j] : 0.0f;
    const float w2   = (j < 5) ? fc2_w[j] : 0.0f;
    const float b2   = fc2_b[0];

    float h = (j < 5) ? hidden[grp * 5 + j] : 0.0f;
    float r[8];
    EXCHANGE(r, h);

    const float* __restrict__ xrow = X  + (size_t)grp * T_;
    float*       __restrict__ yrow = out + (size_t)grp * T_;

    for (int t = 0; t < T_; t += 4) {
        const float4 x4 = *reinterpret_cast<const float4*>(xrow + t);
        float y0, y1, y2, y3;
#pragma unroll
        for (int u = 0; u < 4; ++u) {
            const float x = (u == 0) ? x4.x : (u == 1) ? x4.y : (u == 2) ? x4.z : x4.w;
            float acc = fmaf(x, wih, bias);
            acc = fmaf(w[0], r[0], acc); acc = fmaf(w[1], r[1], acc);
            acc = fmaf(w[2], r[2], acc); acc = fmaf(w[3], r[3], acc);
            acc = fmaf(w[4], r[4], acc); acc = fmaf(w[5], r[5], acc);
            acc = fmaf(w[6], r[6], acc); acc = fmaf(w[7], r[7], acc);
            h = precise_tanh(acc);
            EXCHANGE(r, h);
            float g = fb;
            g = fmaf(f[0], r[0], g); g = fmaf(f[1], r[1], g);
            g = fmaf(f[2], r[2], g); g = fmaf(f[3], r[3], g);
            g = fmaf(f[4], r[4], g); g = fmaf(f[5], r[5], g);
            g = fmaf(f[6], r[6], g); g = fmaf(f[7], r[7], g);
            const float hid = fmaxf(g, 0.0f);
            float p = hid * w2;
            p += DPPF(p, QP_X1);
            p += DPPF(p, QP_X2);
            p += DPPF(p, RHM);
            const float y = p + b2;
            if (u == 0) y0 = y; else if (u == 1) y1 = y; else if (u == 2) y2 = y; else y3 = y;
        }
        if (j == 0) {
            *reinterpret_cast<float4*>(yrow + t) = make_float4(y0, y1, y2, y3);
        }
    }
}

extern "C" void kernel_launch(void* const* d_in, const int* in_sizes, int n_in,
                              void* d_out, int out_size, void* d_ws, size_t ws_size,
                              hipStream_t stream)
{
    const float* hidden = (const float*)d_in[0];
    const float* X      = (const float*)d_in[1];
    const float* W_ih   = (const float*)d_in[2];
    const float* W_hh   = (const float*)d_in[3];
    const float* b_ih   = (const float*)d_in[4];
    const float* b_hh   = (const float*)d_in[5];
    const float* fc1_w  = (const float*)d_in[6];
    const float* fc1_b  = (const float*)d_in[7];
    const float* fc2_w  = (const float*)d_in[8];
    const float* fc2_b  = (const float*)d_in[9];
    float* out = (float*)d_out;

    const size_t need = (size_t)B_ * T_ * 8 * sizeof(float);  // 268 MB
    if (ws_size >= need) {
        float4* hbuf = (float4*)d_ws;
        rnn_phase1<<<dim3(B_ * 8 / 64), dim3(64), 0, stream>>>(
            hidden, X, W_ih, W_hh, b_ih, b_hh, hbuf);
        fc_phase2<<<dim3(B_ * T_ / 4 / 256), dim3(256), 0, stream>>>(
            hbuf, fc1_w, fc1_b, fc2_w, fc2_b, out);
    } else {
        wavernn_fused<<<dim3(B_ * 8 / 64), dim3(64), 0, stream>>>(
            hidden, X, W_ih, W_hh, b_ih, b_hh, fc1_w, fc1_b, fc2_w, fc2_b, out);
    }
}

// Round 11
// 347.319 us; speedup vs baseline: 1.0823x; 1.0823x over previous
//
#include <hip/hip_runtime.h>
#include <math.h>

// WaveRNN: B=4096, T=2048, H=5 tanh RNN + fc1(5x5)+relu + fc2(1x5), fused.
// One batch element per 8-lane group; lane j owns h_j; DPP exchange.
// R7 fused: 275us steady (322 cyc/step), absmax 0.02929688.
// R9 split experiment: removing fc1/fc2/store saved only 30 cyc/step ->
// kernel is dependence-CHAIN-latency bound (~22 chain ops x ~14 cyc);
// off-chain work is free. Reverted to fused.
// R10 (this): bit-identical chain trims:
//  - clamp removed (|acc| <= ~5.6 << 15, provably inactive)
//  - y2=2x folded into constants: a = x*(2*L_hi) == (2x)*L_hi exactly
//    (x2 is an exact exponent bump; fma remainders identical)
// Chain: 8 fma -> a -> e0 -> e -> d -> r0 -> n1 -> n2 -> h  (~19 vs ~22 ops)

#define B_ 4096
#define T_ 2048

#define DPPF(v, ctrl) __int_as_float(__builtin_amdgcn_update_dpp(0, __float_as_int(v), (ctrl), 0xF, 0xF, true))
#define QP_X1 0xB1   // lane l <- l^1
#define QP_X2 0x4E   // lane l <- l^2
#define QP_X3 0x1B   // lane l <- l^3
#define RHM   0x141  // lane l <- l^7 (within 8)

__device__ __forceinline__ float precise_tanh(float x) {
    // tanh(x) = 1 - 2/(exp2(x*2log2e)+1); compensated argument +
    // Newton-refined rcp. Bit-identical to the clamped y2-form for |x|<15.
    const float TWOL_hi = 2.0f * 1.44269504f;    // exact (exponent bump)
    const float TWOL_lo = 2.0f * 1.9259630e-8f;  // exact
    const float LN2     = 0.69314718f;

    float a  = x * TWOL_hi;
    float dl = fmaf(x, TWOL_hi, -a);             // exact product remainder
    dl = fmaf(x, TWOL_lo, dl);                   // + tail of 2*log2e
    float e0 = __builtin_amdgcn_exp2f(a);
    float e  = fmaf(e0, dl * LN2, e0);           // E = e0*(1 + dl*ln2)
    float d  = e + 1.0f;
    float r0 = __builtin_amdgcn_rcpf(d);
    float r  = fmaf(fmaf(-d, r0, 1.0f), r0, r0); // one Newton step
    return fmaf(-2.0f, r, 1.0f);
}

#define EXCHANGE(rr, hh)                                   \
    do {                                                   \
        rr[0] = (hh);                                      \
        rr[1] = DPPF((hh), QP_X1);                         \
        rr[2] = DPPF((hh), QP_X2);                         \
        rr[3] = DPPF((hh), QP_X3);                         \
        rr[7] = DPPF((hh), RHM);                           \
        rr[6] = DPPF(rr[7], QP_X1);                        \
        rr[5] = DPPF(rr[7], QP_X2);                        \
        rr[4] = DPPF(rr[7], QP_X3);                        \
    } while (0)

__global__ __launch_bounds__(64, 1) void wavernn_kernel(
    const float* __restrict__ hidden, const float* __restrict__ X,
    const float* __restrict__ W_ih, const float* __restrict__ W_hh,
    const float* __restrict__ b_ih, const float* __restrict__ b_hh,
    const float* __restrict__ fc1_w, const float* __restrict__ fc1_b,
    const float* __restrict__ fc2_w, const float* __restrict__ fc2_b,
    float* __restrict__ out)
{
    const int lane = threadIdx.x;                    // 0..63
    const int j = lane & 7;                          // position in 8-lane group
    const int grp = (blockIdx.x * 64 + lane) >> 3;   // batch element, 0..4095

    float w[8], f[8];
#pragma unroll
    for (int k = 0; k < 8; ++k) {
        const int c = j ^ k;
        const bool live = (j < 5) && (c < 5);
        w[k] = live ? W_hh[j * 5 + c] : 0.0f;
        f[k] = live ? fc1_w[j * 5 + c] : 0.0f;
    }
    const float wih  = (j < 5) ? W_ih[j] : 0.0f;
    const float bias = (j < 5) ? (b_ih[j] + b_hh[j]) : 0.0f;
    const float fb   = (j < 5) ? fc1_b[j] : 0.0f;
    const float w2   = (j < 5) ? fc2_w[j] : 0.0f;
    const float b2   = fc2_b[0];

    float h = (j < 5) ? hidden[grp * 5 + j] : 0.0f;
    float r[8];
    EXCHANGE(r, h);

    const float* __restrict__ xrow = X  + (size_t)grp * T_;
    float*       __restrict__ yrow = out + (size_t)grp * T_;

    for (int t = 0; t < T_; t += 4) {
        const float4 x4 = *reinterpret_cast<const float4*>(xrow + t);
        float y0, y1, y2, y3;
#pragma unroll
        for (int u = 0; u < 4; ++u) {
            const float x = (u == 0) ? x4.x : (u == 1) ? x4.y : (u == 2) ? x4.z : x4.w;

            // acc = x*W_ih[j] + (b_ih+b_hh)[j] + sum_c W_hh[j][c]*h_prev[c]
            // (same fma order as verified R7 kernel -> bit-identical)
            float acc = fmaf(x, wih, bias);
            acc = fmaf(w[0], r[0], acc); acc = fmaf(w[1], r[1], acc);
            acc = fmaf(w[2], r[2], acc); acc = fmaf(w[3], r[3], acc);
            acc = fmaf(w[4], r[4], acc); acc = fmaf(w[5], r[5], acc);
            acc = fmaf(w[6], r[6], acc); acc = fmaf(w[7], r[7], acc);
            h = precise_tanh(acc);       // lanes 5..7 stay exactly 0

            EXCHANGE(r, h);              // feeds fc1 now and the dot next step

            // fc1 row j + relu  (off the dataflow chain -> ~free)
            float g = fb;
            g = fmaf(f[0], r[0], g); g = fmaf(f[1], r[1], g);
            g = fmaf(f[2], r[2], g); g = fmaf(f[3], r[3], g);
            g = fmaf(f[4], r[4], g); g = fmaf(f[5], r[5], g);
            g = fmaf(f[6], r[6], g); g = fmaf(f[7], r[7], g);
            const float hid = fmaxf(g, 0.0f);

            // fc2: 8-lane butterfly (p quad-uniform after XOR1+XOR2, so RHM
            // partner == XOR4 partner -> bit-identical to swizzle version)
            float p = hid * w2;
            p += DPPF(p, QP_X1);
            p += DPPF(p, QP_X2);
            p += DPPF(p, RHM);
            const float y = p + b2;
            if (u == 0) y0 = y; else if (u == 1) y1 = y; else if (u == 2) y2 = y; else y3 = y;
        }
        if (j == 0) {
            *reinterpret_cast<float4*>(yrow + t) = make_float4(y0, y1, y2, y3);
        }
    }
}

extern "C" void kernel_launch(void* const* d_in, const int* in_sizes, int n_in,
                              void* d_out, int out_size, void* d_ws, size_t ws_size,
                              hipStream_t stream)
{
    const float* hidden = (const float*)d_in[0];
    const float* X      = (const float*)d_in[1];
    const float* W_ih   = (const float*)d_in[2];
    const float* W_hh   = (const float*)d_in[3];
    const float* b_ih   = (const float*)d_in[4];
    const float* b_hh   = (const float*)d_in[5];
    const float* fc1_w  = (const float*)d_in[6];
    const float* fc1_b  = (const float*)d_in[7];
    const float* fc2_w  = (const float*)d_in[8];
    const float* fc2_b  = (const float*)d_in[9];
    float* out = (float*)d_out;

    wavernn_kernel<<<dim3(B_ * 8 / 64), dim3(64), 0, stream>>>(
        hidden, X, W_ih, W_hh, b_ih, b_hh, fc1_w, fc1_b, fc2_w, fc2_b, out);
}

// Round 12
// 339.976 us; speedup vs baseline: 1.1057x; 1.0216x over previous
//
#include <hip/hip_runtime.h>
#include <math.h>

// WaveRNN: B=4096, T=2048, H=5 tanh RNN + fc1(5x5)+relu + fc2(1x5), fused.
// One batch element per 8-lane group; lane j owns h_j; DPP exchange.
// R7: 275us steady. R9 split: off-chain work ~free (1.4cyc/inst). R11 trim:
// -3 chain ops -> -10cyc (dep latency ~3-4cyc/op). Accounting: chain ~90cyc +
// issue ~60cyc != 312cyc measured -> ~160cyc/step unexplained = X-load stall
// (float4 load consumed immediately each 4-step iter; single in-order wave
// eats full load-to-use latency every iteration).
// R12 (this): software-pipeline the X load one iteration ahead (clamped
// index). Arithmetic untouched -> absmax must stay exactly 0.02929688.

#define B_ 4096
#define T_ 2048

#define DPPF(v, ctrl) __int_as_float(__builtin_amdgcn_update_dpp(0, __float_as_int(v), (ctrl), 0xF, 0xF, true))
#define QP_X1 0xB1   // lane l <- l^1
#define QP_X2 0x4E   // lane l <- l^2
#define QP_X3 0x1B   // lane l <- l^3
#define RHM   0x141  // lane l <- l^7 (within 8)

__device__ __forceinline__ float precise_tanh(float x) {
    // tanh(x) = 1 - 2/(exp2(x*2log2e)+1); compensated argument +
    // Newton-refined rcp. (R10 form, verified absmax 0.02929688.)
    const float TWOL_hi = 2.0f * 1.44269504f;    // exact (exponent bump)
    const float TWOL_lo = 2.0f * 1.9259630e-8f;  // exact
    const float LN2     = 0.69314718f;

    float a  = x * TWOL_hi;
    float dl = fmaf(x, TWOL_hi, -a);             // exact product remainder
    dl = fmaf(x, TWOL_lo, dl);                   // + tail of 2*log2e
    float e0 = __builtin_amdgcn_exp2f(a);
    float e  = fmaf(e0, dl * LN2, e0);           // E = e0*(1 + dl*ln2)
    float d  = e + 1.0f;
    float r0 = __builtin_amdgcn_rcpf(d);
    float r  = fmaf(fmaf(-d, r0, 1.0f), r0, r0); // one Newton step
    return fmaf(-2.0f, r, 1.0f);
}

#define EXCHANGE(rr, hh)                                   \
    do {                                                   \
        rr[0] = (hh);                                      \
        rr[1] = DPPF((hh), QP_X1);                         \
        rr[2] = DPPF((hh), QP_X2);                         \
        rr[3] = DPPF((hh), QP_X3);                         \
        rr[7] = DPPF((hh), RHM);                           \
        rr[6] = DPPF(rr[7], QP_X1);                        \
        rr[5] = DPPF(rr[7], QP_X2);                        \
        rr[4] = DPPF(rr[7], QP_X3);                        \
    } while (0)

__global__ __launch_bounds__(64, 1) void wavernn_kernel(
    const float* __restrict__ hidden, const float* __restrict__ X,
    const float* __restrict__ W_ih, const float* __restrict__ W_hh,
    const float* __restrict__ b_ih, const float* __restrict__ b_hh,
    const float* __restrict__ fc1_w, const float* __restrict__ fc1_b,
    const float* __restrict__ fc2_w, const float* __restrict__ fc2_b,
    float* __restrict__ out)
{
    const int lane = threadIdx.x;                    // 0..63
    const int j = lane & 7;                          // position in 8-lane group
    const int grp = (blockIdx.x * 64 + lane) >> 3;   // batch element, 0..4095

    float w[8], f[8];
#pragma unroll
    for (int k = 0; k < 8; ++k) {
        const int c = j ^ k;
        const bool live = (j < 5) && (c < 5);
        w[k] = live ? W_hh[j * 5 + c] : 0.0f;
        f[k] = live ? fc1_w[j * 5 + c] : 0.0f;
    }
    const float wih  = (j < 5) ? W_ih[j] : 0.0f;
    const float bias = (j < 5) ? (b_ih[j] + b_hh[j]) : 0.0f;
    const float fb   = (j < 5) ? fc1_b[j] : 0.0f;
    const float w2   = (j < 5) ? fc2_w[j] : 0.0f;
    const float b2   = fc2_b[0];

    float h = (j < 5) ? hidden[grp * 5 + j] : 0.0f;
    float r[8];
    EXCHANGE(r, h);

    const float4* __restrict__ xrow4 = reinterpret_cast<const float4*>(X + (size_t)grp * T_);
    float*        __restrict__ yrow  = out + (size_t)grp * T_;

    float4 xc = xrow4[0];                      // current iteration's x block
    for (int tq = 0; tq < T_ / 4; ++tq) {
        // Prefetch next block NOW; consumed only next iteration, so the
        // ~200-900cy load latency hides under this iteration's ~1200cy compute.
        const int tn = (tq + 1 < T_ / 4) ? (tq + 1) : tq;   // clamped (no branch)
        const float4 xn = xrow4[tn];

        float y0, y1, y2, y3;
#pragma unroll
        for (int u = 0; u < 4; ++u) {
            const float x = (u == 0) ? xc.x : (u == 1) ? xc.y : (u == 2) ? xc.z : xc.w;

            // acc = x*W_ih[j] + (b_ih+b_hh)[j] + sum_c W_hh[j][c]*h_prev[c]
            // (same fma order as verified R7/R10 kernels -> bit-identical)
            float acc = fmaf(x, wih, bias);
            acc = fmaf(w[0], r[0], acc); acc = fmaf(w[1], r[1], acc);
            acc = fmaf(w[2], r[2], acc); acc = fmaf(w[3], r[3], acc);
            acc = fmaf(w[4], r[4], acc); acc = fmaf(w[5], r[5], acc);
            acc = fmaf(w[6], r[6], acc); acc = fmaf(w[7], r[7], acc);
            h = precise_tanh(acc);       // lanes 5..7 stay exactly 0

            EXCHANGE(r, h);              // feeds fc1 now and the dot next step

            // fc1 row j + relu  (off the dataflow chain -> ~free)
            float g = fb;
            g = fmaf(f[0], r[0], g); g = fmaf(f[1], r[1], g);
            g = fmaf(f[2], r[2], g); g = fmaf(f[3], r[3], g);
            g = fmaf(f[4], r[4], g); g = fmaf(f[5], r[5], g);
            g = fmaf(f[6], r[6], g); g = fmaf(f[7], r[7], g);
            const float hid = fmaxf(g, 0.0f);

            // fc2: 8-lane butterfly (p quad-uniform after XOR1+XOR2, so RHM
            // partner == XOR4 partner -> bit-identical)
            float p = hid * w2;
            p += DPPF(p, QP_X1);
            p += DPPF(p, QP_X2);
            p += DPPF(p, RHM);
            const float y = p + b2;
            if (u == 0) y0 = y; else if (u == 1) y1 = y; else if (u == 2) y2 = y; else y3 = y;
        }
        if (j == 0) {
            *reinterpret_cast<float4*>(yrow + 4 * tq) = make_float4(y0, y1, y2, y3);
        }
        xc = xn;
    }
}

extern "C" void kernel_launch(void* const* d_in, const int* in_sizes, int n_in,
                              void* d_out, int out_size, void* d_ws, size_t ws_size,
                              hipStream_t stream)
{
    const float* hidden = (const float*)d_in[0];
    const float* X      = (const float*)d_in[1];
    const float* W_ih   = (const float*)d_in[2];
    const float* W_hh   = (const float*)d_in[3];
    const float* b_ih   = (const float*)d_in[4];
    const float* b_hh   = (const float*)d_in[5];
    const float* fc1_w  = (const float*)d_in[6];
    const float* fc1_b  = (const float*)d_in[7];
    const float* fc2_w  = (const float*)d_in[8];
    const float* fc2_b  = (const float*)d_in[9];
    float* out = (float*)d_out;

    wavernn_kernel<<<dim3(B_ * 8 / 64), dim3(64), 0, stream>>>(
        hidden, X, W_ih, W_hh, b_ih, b_hh, fc1_w, fc1_b, fc2_w, fc2_b, out);
}